// Round 11
// baseline (653.018 us; speedup 1.0000x reference)
//
#include <hip/hip_runtime.h>
#include <hip/hip_bf16.h>
#include <type_traits>

// ConversationGNN: encoder Linear(386->384) -> GAT(384 -> 4x256 concat) -> ELU
//                  -> GAT(1024 -> 128, 1 head) ; N=50000, E=500000 (+N self loops)
// Round 21: XCD-AWARE GEMM GRID SWIZZLE. agg1's counters proved per-XCD L2s
// each pay their own compulsory fetch (565MB for a 102MB buffer = 8x per-XCD
// footprint). GEMM1's default dispatch spreads the 8 col-tiles of one A
// row-panel across 8 XCDs -> A fetched ~8x (307MB). Swizzle: linear grid,
// xcd=i&7, x=(i>>3)/YB*8+xcd, y=(i>>3)%YB -> all y-tiles of a row-panel land
// on ONE XCD consecutively (A-panel L2-resident, fetched once). Encoder same
// (YB=3). GEMM2 has 1 y-tile (no reuse) - unswizzled. Everything else =
// round-20 (646.5us: fuseA, scan3b, global_load_lds GEMM staging, round-12
// agg kernels; agg1 at its ~4.05 TB/s random-gather ceiling).

#define NN 50000
#define NE 500000
#define EP (NE + NN)

typedef __hip_bfloat16 bf16;
typedef short short8 __attribute__((ext_vector_type(8)));
typedef __bf16 bf16x8 __attribute__((ext_vector_type(8)));
typedef float f32x4 __attribute__((ext_vector_type(4)));

__device__ __forceinline__ float b2f(bf16 v) { return __bfloat162float(v); }
__device__ __forceinline__ bf16  f2b(float v) { return __float2bfloat16(v); }
__device__ __forceinline__ unsigned short f2bu(float v) {
  bf16 b = __float2bfloat16(v);
  return *reinterpret_cast<unsigned short*>(&b);
}

__device__ __forceinline__ float ldf(const void* p, size_t i, bool f32) {
  return f32 ? ((const float*)p)[i] : b2f(((const bf16*)p)[i]);
}

// unpack two bf16 from one u32 word
__device__ __forceinline__ float bflo(unsigned u) { return __uint_as_float(u << 16); }
__device__ __forceinline__ float bfhi(unsigned u) { return __uint_as_float(u & 0xffff0000u); }

__device__ __forceinline__ float leaky(float v) { return v >= 0.f ? v : 0.2f * v; }

// async 16B global->LDS copy (dest = wave-uniform base + lane*16)
__device__ __forceinline__ void gload_lds16(const void* g, void* l) {
  __builtin_amdgcn_global_load_lds(
      (const __attribute__((address_space(1))) void*)g,
      (__attribute__((address_space(3))) void*)l, 16, 0, 0);
}

// ---------------- fused dtype detection ----------------------------------
__global__ void k_detect(const unsigned int* __restrict__ ei,
                         const unsigned int* __restrict__ xw,
                         unsigned int* __restrict__ eflag,
                         unsigned int* __restrict__ fflag) {
  const int b = blockIdx.x;
  if (b < 512) {
    unsigned int acc = 0;
    for (int i = b * 256 + threadIdx.x; i < NE; i += 512 * 256)
      acc |= ei[2 * i + 1];
    if (acc) atomicOr(eflag, 1u);
  } else {
    unsigned int acc = 0;
    for (int i = (b - 512) * 256 + threadIdx.x; i < (1 << 20); i += 256 * 256) {
      unsigned int e = (xw[i] >> 7) & 0xFF;
      if (e > 0xA0) acc = 1;
    }
    if (acc) atomicOr(fflag, 1u);
  }
}

// ---------------- fused convert + pack (one dispatch) ---------------------
#define PW_S0 (416 * 384)
#define PW_S1 (384 * 1024)
#define PW_S2 (1024 * 128)
#define FUSE_T1 EP
#define FUSE_T2 (FUSE_T1 + NN * 104)
#define FUSE_T3 (FUSE_T2 + PW_S0 + PW_S1 + PW_S2)

__global__ void k_fuseA(const int* __restrict__ ei,
                        const void* __restrict__ x, const void* __restrict__ na,
                        const void* __restrict__ Wenc, const void* __restrict__ W1,
                        const void* __restrict__ W2,
                        int* __restrict__ esrc, int* __restrict__ edst,
                        int* __restrict__ deg,
                        bf16* __restrict__ catp, bf16* __restrict__ encWp,
                        bf16* __restrict__ W1p, bf16* __restrict__ W2p,
                        const unsigned int* __restrict__ eflag,
                        const unsigned int* __restrict__ fflag) {
  const bool ef  = (*eflag != 0);
  const bool f32 = (*fflag != 0);
  for (int g = blockIdx.x * 256 + threadIdx.x; g < FUSE_T3; g += gridDim.x * 256) {
    if (g < FUSE_T1) {
      // convert + degree histogram
      const int e = g;
      int s, d;
      if (e < NE) {
        if (ef) { s = ei[e]; d = ei[NE + e]; }
        else { const long long* e64 = (const long long*)ei; s = (int)e64[e]; d = (int)e64[NE + e]; }
        s = min(max(s, 0), NN - 1);
        d = min(max(d, 0), NN - 1);
      } else {
        s = d = e - NE;
      }
      esrc[e] = s;
      edst[e] = d;
      atomicAdd(&deg[d], 1);
    } else if (g < FUSE_T2) {
      // pack_cat: catp [NN][416] = [x(384); na(2); pad(30)]
      const int gg = g - FUSE_T1;
      int n = gg / 104, r = gg - n * 104;
      int c = r * 4;
      float v0 = 0.f, v1 = 0.f, v2 = 0.f, v3 = 0.f;
      if (c < 384) {
        if (f32) {
          const float4 f = *(const float4*)((const float*)x + (size_t)n * 384 + c);
          v0 = f.x; v1 = f.y; v2 = f.z; v3 = f.w;
        } else {
          const bf16* xb = (const bf16*)x + (size_t)n * 384 + c;
          v0 = b2f(xb[0]); v1 = b2f(xb[1]); v2 = b2f(xb[2]); v3 = b2f(xb[3]);
        }
      } else if (c == 384) {
        v0 = ldf(na, (size_t)n * 2 + 0, f32);
        v1 = ldf(na, (size_t)n * 2 + 1, f32);
      }
      ushort2 o0, o1;
      o0.x = f2bu(v0); o0.y = f2bu(v1);
      o1.x = f2bu(v2); o1.y = f2bu(v3);
      ushort2* dst = (ushort2*)((unsigned short*)catp + (size_t)n * 416 + c);
      dst[0] = o0; dst[1] = o1;
    } else {
      // pack_w3
      int i = g - FUSE_T2;
      const void* W; bf16* Wp; int K, N;
      if (i < PW_S0)               { W = Wenc; Wp = encWp; K = 386;  N = 384;  }
      else if (i < PW_S0 + PW_S1)  { W = W1;   Wp = W1p;   K = 384;  N = 1024; i -= PW_S0; }
      else                         { W = W2;   Wp = W2p;   K = 1024; N = 128;  i -= PW_S0 + PW_S1; }
      int kb = i / (N * 32);
      int rem = i - kb * N * 32;
      int n = rem >> 5, kk = rem & 31;
      int k = kb * 32 + kk;
      float v = (k < K) ? ldf(W, (size_t)k * N + n, f32) : 0.f;
      Wp[i] = f2b(v);
    }
  }
}

// ---------------- CSR scan (2 dispatches) ---------------------------------
#define SCAN_B 512
#define SCAN_NB ((NN + SCAN_B - 1) / SCAN_B)   // 98

__global__ __launch_bounds__(SCAN_B) void k_scan1(const int* __restrict__ deg,
                                                  int* __restrict__ row_ptr,
                                                  int* __restrict__ partial) {
  int b = blockIdx.x, t = threadIdx.x;
  int i = b * SCAN_B + t;
  int v = (i < NN) ? deg[i] : 0;
  int lane = t & 63, w = t >> 6;
  int x = v;
#pragma unroll
  for (int off = 1; off < 64; off <<= 1) {
    int y = __shfl_up(x, off, 64);
    if (lane >= off) x += y;
  }
  __shared__ int ws[8];
  if (lane == 63) ws[w] = x;
  __syncthreads();
  if (t == 0) {
    int run = 0;
#pragma unroll
    for (int j = 0; j < 8; ++j) { int tmp = ws[j]; ws[j] = run; run += tmp; }
    partial[b] = run;
  }
  __syncthreads();
  int excl = x - v + ws[w];
  if (i < NN) row_ptr[i] = excl;
}

// scan3b: each block computes its own chunk-prefix from the 98 partials
// (LDS-cached, uniform loop) — eliminates the separate k_scan2 dispatch.
__global__ __launch_bounds__(SCAN_B) void k_scan3b(const int* __restrict__ partial,
                                                   int* __restrict__ row_ptr,
                                                   int* __restrict__ cursor) {
  const int b = blockIdx.x, t = threadIdx.x;
  __shared__ int sp[SCAN_NB];
  for (int j = t; j < SCAN_NB; j += SCAN_B) sp[j] = partial[j];
  __syncthreads();
  int prefix = 0;
  for (int j = 0; j < b; ++j) prefix += sp[j];   // uniform per block
  const int i = b * SCAN_B + t;
  if (i < NN) {
    int v = row_ptr[i] + prefix;
    row_ptr[i] = v;
    cursor[i] = v;
  }
  if (b == SCAN_NB - 1 && t == 0)
    row_ptr[NN] = prefix + sp[SCAN_NB - 1];       // == EP
}

__global__ void k_scatter(const int* __restrict__ esrc, const int* __restrict__ edst,
                          int* __restrict__ cursor, int* __restrict__ csr) {
  int e = blockIdx.x * 256 + threadIdx.x;
  if (e >= EP) return;
  int pos = atomicAdd(&cursor[edst[e]], 1);
  pos = min(max(pos, 0), EP - 1);
  csr[pos] = esrc[e];
}

// ---------------- MFMA GEMM with fused alpha epilogue --------------------
// Bp packed [K/32][N][32] bf16. N multiple of 128, K multiple of 32.
// 128x128 tile, 4 waves 2x2, each wave 4x4 of 16x16x32 MFMAs.
// Staging: global_load_lds width-16 into LINEAR LDS tiles [128][32].
// YB>0: XCD-aware swizzled 1D grid — xcd=i&7, x=(i>>3)/YB*8+xcd, y=(i>>3)%YB
// so all YB col-tiles of one A row-panel run on the same XCD (A fetched once
// per XCD instead of YB times). YB=0: plain 2D grid.
template<bool ADD_BIAS, bool ALPHA, int NH, int YB, typename CT>
__global__ __launch_bounds__(256) void gemm_mfma(
    const bf16* __restrict__ A, int lda,
    const bf16* __restrict__ Bp,
    const void* __restrict__ bias,
    const void* __restrict__ a_srcp, const void* __restrict__ a_dstp,
    float* __restrict__ as_out, float* __restrict__ ad_out,
    CT* __restrict__ C,
    int M, int N, int K,
    const unsigned int* __restrict__ fflag) {
  const bool xf32 = (ADD_BIAS || ALPHA) ? (*fflag != 0) : false;
  __shared__ short As[128 * 32];
  __shared__ short Bs[128 * 32];
  const int t = threadIdx.x;
  const int lane = t & 63, wave = t >> 6;
  const int wm = wave & 1, wn = wave >> 1;
  const int quad = lane >> 4, l15 = lane & 15;

  int bx, by;
  if constexpr (YB > 0) {
    const int i = blockIdx.x;
    const int xcd = i & 7;
    const int k = i >> 3;
    by = k % YB;
    bx = (k / YB) * 8 + xcd;
    if (bx >= ((M + 127) >> 7)) return;
  } else {
    bx = blockIdx.x; by = blockIdx.y;
  }
  const int m0 = bx * 128, n0 = by * 128;

  f32x4 acc[4][4];
#pragma unroll
  for (int i = 0; i < 4; ++i)
#pragma unroll
    for (int j = 0; j < 4; ++j) acc[i][j] = (f32x4){0.f, 0.f, 0.f, 0.f};

  // per-thread staging geometry (k-invariant)
  const int c0 = t, c1 = t + 256;
  const int arow0 = min(m0 + (c0 >> 2), M - 1), akoff0 = (c0 & 3) * 8;
  const int arow1 = min(m0 + (c1 >> 2), M - 1), akoff1 = (c1 & 3) * 8;

  for (int k0 = 0; k0 < K; k0 += 32) {
    gload_lds16((const short*)A + (size_t)arow0 * lda + k0 + akoff0, &As[c0 * 8]);
    gload_lds16((const short*)A + (size_t)arow1 * lda + k0 + akoff1, &As[c1 * 8]);
    {
      const short* base = (const short*)Bp + ((size_t)(k0 >> 5) * N + n0) * 32;
      gload_lds16(base + c0 * 8, &Bs[c0 * 8]);
      gload_lds16(base + c1 * 8, &Bs[c1 * 8]);
    }
    __syncthreads();
    bf16x8 af[4], bfr[4];
#pragma unroll
    for (int mi = 0; mi < 4; ++mi)
      af[mi] = *reinterpret_cast<const bf16x8*>(&As[(wm * 64 + mi * 16 + l15) * 32 + quad * 8]);
#pragma unroll
    for (int ni = 0; ni < 4; ++ni)
      bfr[ni] = *reinterpret_cast<const bf16x8*>(&Bs[(wn * 64 + ni * 16 + l15) * 32 + quad * 8]);
#pragma unroll
    for (int mi = 0; mi < 4; ++mi)
#pragma unroll
      for (int ni = 0; ni < 4; ++ni)
        acc[mi][ni] = __builtin_amdgcn_mfma_f32_16x16x32_bf16(af[mi], bfr[ni], acc[mi][ni], 0, 0, 0);
    __syncthreads();
  }

  // C write (C/D layout: col=lane&15, row=quad*4+reg)
#pragma unroll
  for (int mi = 0; mi < 4; ++mi) {
#pragma unroll
    for (int ni = 0; ni < 4; ++ni) {
      const int gn = n0 + wn * 64 + ni * 16 + l15;
      float bv = ADD_BIAS ? ldf(bias, gn, xf32) : 0.f;
#pragma unroll
      for (int r = 0; r < 4; ++r) {
        const int gm = m0 + wm * 64 + mi * 16 + quad * 4 + r;
        if (gm < M) {
          float v = acc[mi][ni][r] + bv;
          if constexpr (std::is_same<CT, float>::value)
            C[(size_t)gm * N + gn] = v;
          else
            C[(size_t)gm * N + gn] = f2b(v);
        }
      }
    }
  }

  if (ALPHA) {
    // a_src/a_dst flat [N]: flat index == gn for both layer shapes.
    float avs[4], avd[4];
#pragma unroll
    for (int ni = 0; ni < 4; ++ni) {
      const int gn = n0 + wn * 64 + ni * 16 + l15;
      avs[ni] = ldf(a_srcp, gn, xf32);
      avd[ni] = ldf(a_dstp, gn, xf32);
    }
    const int head = (n0 + wn * 64) >> 8;
#pragma unroll
    for (int mi = 0; mi < 4; ++mi) {
#pragma unroll
      for (int r = 0; r < 4; ++r) {
        float ps = 0.f, pd = 0.f;
#pragma unroll
        for (int ni = 0; ni < 4; ++ni) {
          const float v = acc[mi][ni][r];
          ps = fmaf(v, avs[ni], ps);
          pd = fmaf(v, avd[ni], pd);
        }
#pragma unroll
        for (int off = 8; off > 0; off >>= 1) {
          ps += __shfl_down(ps, off, 16);
          pd += __shfl_down(pd, off, 16);
        }
        if (l15 == 0) {
          const int gm = m0 + wm * 64 + mi * 16 + quad * 4 + r;
          if (gm < M) {
            atomicAdd(&as_out[gm * NH + head], ps);
            atomicAdd(&ad_out[gm * NH + head], pd);
          }
        }
      }
    }
  }
}

// ---------------- fused softmax + aggregation ----------------------------
// k_agg1: block = dst node n; wave w = head w; lane l covers cols
// w*128+l*2 (two dwords = 4 bf16). Batch-4 + serial tail (round-12 form —
// measured best; agg1 is at the ~4.05 TB/s random-gather channel ceiling).
__global__ __launch_bounds__(256) void k_agg1(
    const int* __restrict__ csr, const int* __restrict__ row_ptr,
    const float* __restrict__ as1, const float* __restrict__ ad1,
    const bf16* __restrict__ h1, const void* __restrict__ b1,
    bf16* __restrict__ act1, const unsigned int* __restrict__ fflag) {
  const bool f32 = (*fflag != 0);
  const int n = blockIdx.x, t = threadIdx.x;
  const int w = t >> 6, l = t & 63;
  const int start = row_ptr[n], end = row_ptr[n + 1];
  const float adn = ad1[n * 4 + w];
  const unsigned* hb = (const unsigned*)h1;
  const int coff = w * 128 + l * 2;

  float a0 = 0.f, a1 = 0.f, a2 = 0.f, a3 = 0.f, densum = 0.f;

  int idx = start;
  for (; idx + 4 <= end; idx += 4) {
    int s0 = csr[idx], s1 = csr[idx + 1], s2 = csr[idx + 2], s3 = csr[idx + 3];
    uint2 w0 = *(const uint2*)(hb + (size_t)s0 * 512 + coff);
    uint2 w1 = *(const uint2*)(hb + (size_t)s1 * 512 + coff);
    uint2 w2 = *(const uint2*)(hb + (size_t)s2 * 512 + coff);
    uint2 w3 = *(const uint2*)(hb + (size_t)s3 * 512 + coff);
    float p0 = __expf(leaky(as1[s0 * 4 + w] + adn));
    float p1 = __expf(leaky(as1[s1 * 4 + w] + adn));
    float p2 = __expf(leaky(as1[s2 * 4 + w] + adn));
    float p3 = __expf(leaky(as1[s3 * 4 + w] + adn));
    densum += (p0 + p1) + (p2 + p3);
    a0 = fmaf(bflo(w0.x), p0, a0); a1 = fmaf(bfhi(w0.x), p0, a1);
    a2 = fmaf(bflo(w0.y), p0, a2); a3 = fmaf(bfhi(w0.y), p0, a3);
    a0 = fmaf(bflo(w1.x), p1, a0); a1 = fmaf(bfhi(w1.x), p1, a1);
    a2 = fmaf(bflo(w1.y), p1, a2); a3 = fmaf(bfhi(w1.y), p1, a3);
    a0 = fmaf(bflo(w2.x), p2, a0); a1 = fmaf(bfhi(w2.x), p2, a1);
    a2 = fmaf(bflo(w2.y), p2, a2); a3 = fmaf(bfhi(w2.y), p2, a3);
    a0 = fmaf(bflo(w3.x), p3, a0); a1 = fmaf(bfhi(w3.x), p3, a1);
    a2 = fmaf(bflo(w3.y), p3, a2); a3 = fmaf(bfhi(w3.y), p3, a3);
  }
  for (; idx < end; ++idx) {
    int s0 = csr[idx];
    uint2 w0 = *(const uint2*)(hb + (size_t)s0 * 512 + coff);
    float p0 = __expf(leaky(as1[s0 * 4 + w] + adn));
    densum += p0;
    a0 = fmaf(bflo(w0.x), p0, a0); a1 = fmaf(bfhi(w0.x), p0, a1);
    a2 = fmaf(bflo(w0.y), p0, a2); a3 = fmaf(bfhi(w0.y), p0, a3);
  }

  const float inv = 1.f / (densum + 1e-16f);
  const int col = w * 256 + l * 4;
  float v0 = a0 * inv + ldf(b1, col + 0, f32);
  float v1 = a1 * inv + ldf(b1, col + 1, f32);
  float v2 = a2 * inv + ldf(b1, col + 2, f32);
  float v3 = a3 * inv + ldf(b1, col + 3, f32);
  v0 = v0 > 0.f ? v0 : expm1f(v0);
  v1 = v1 > 0.f ? v1 : expm1f(v1);
  v2 = v2 > 0.f ? v2 : expm1f(v2);
  v3 = v3 > 0.f ? v3 : expm1f(v3);
  unsigned lo = (unsigned)f2bu(v0) | ((unsigned)f2bu(v1) << 16);
  unsigned hi = (unsigned)f2bu(v2) | ((unsigned)f2bu(v3) << 16);
  unsigned long long ow = (unsigned long long)lo | ((unsigned long long)hi << 32);
  __builtin_nontemporal_store(
      ow, (unsigned long long*)((unsigned short*)act1 + (size_t)n * 1024 + col));
}

// k_agg2: ONE WAVE PER NODE (4 nodes / block). Lane l covers channels
// 2l, 2l+1 of the 128-wide h2 row (one dword load per edge). Single head.
// readfirstlane batch-2 (round-12 form). NT store out.
__global__ __launch_bounds__(256) void k_agg2(
    const int* __restrict__ csr, const int* __restrict__ row_ptr,
    const float* __restrict__ as2, const float* __restrict__ ad2,
    const bf16* __restrict__ h2, const void* __restrict__ b2v,
    float* __restrict__ out, const unsigned int* __restrict__ fflag) {
  const bool f32 = (*fflag != 0);
  const int t = threadIdx.x;
  const int wv = t >> 6, l = t & 63;
  const int n = blockIdx.x * 4 + wv;
  const int start = row_ptr[n], end = row_ptr[n + 1];
  const float adn = ad2[n];
  const unsigned* hb = (const unsigned*)h2;   // 64 words per row
  float a0 = 0.f, a1 = 0.f, densum = 0.f;

  int idx = start;
  for (; idx + 2 <= end; idx += 2) {
    const int s0 = __builtin_amdgcn_readfirstlane(csr[idx]);
    const int s1 = __builtin_amdgcn_readfirstlane(csr[idx + 1]);
    const unsigned w0 = hb[(size_t)s0 * 64 + l];
    const unsigned w1 = hb[(size_t)s1 * 64 + l];
    const float p0 = __expf(leaky(as2[s0] + adn));
    const float p1 = __expf(leaky(as2[s1] + adn));
    densum += p0 + p1;
    a0 = fmaf(bflo(w0), p0, a0); a1 = fmaf(bfhi(w0), p0, a1);
    a0 = fmaf(bflo(w1), p1, a0); a1 = fmaf(bfhi(w1), p1, a1);
  }
  if (idx < end) {
    const int s0 = __builtin_amdgcn_readfirstlane(csr[idx]);
    const unsigned w0 = hb[(size_t)s0 * 64 + l];
    const float p0 = __expf(leaky(as2[s0] + adn));
    densum += p0;
    a0 = fmaf(bflo(w0), p0, a0); a1 = fmaf(bfhi(w0), p0, a1);
  }

  const float inv = 1.f / (densum + 1e-16f);
  float2 o;
  o.x = a0 * inv + ldf(b2v, l * 2 + 0, f32);
  o.y = a1 * inv + ldf(b2v, l * 2 + 1, f32);
  unsigned long long u;
  __builtin_memcpy(&u, &o, 8);
  __builtin_nontemporal_store(u, (unsigned long long*)(out + (size_t)n * 128 + l * 2));
}

// ---------------- launch --------------------------------------------------
extern "C" void kernel_launch(void* const* d_in, const int* in_sizes, int n_in,
                              void* d_out, int out_size, void* d_ws, size_t ws_size,
                              hipStream_t stream) {
  const void* x       = d_in[0];
  const void* na      = d_in[1];
  const int*  ei      = (const int*)d_in[2];
  const void* enc_W   = d_in[3];
  const void* enc_b   = d_in[4];
  const void* W1      = d_in[5];
  const void* a_src1  = d_in[6];
  const void* a_dst1  = d_in[7];
  const void* b1      = d_in[8];
  const void* W2      = d_in[9];
  const void* a_src2  = d_in[10];
  const void* a_dst2  = d_in[11];
  const void* b2      = d_in[12];
  float* out = (float*)d_out;

  size_t off = 0;
  char* ws = (char*)d_ws;
  auto alloc = [&](size_t bytes) -> void* {
    void* p = ws + off;
    off += (bytes + 255) & ~(size_t)255;
    return p;
  };
  bf16*  h1      = (bf16*)alloc((size_t)NN * 1024 * 2);
  bf16*  act1    = (bf16*)alloc((size_t)NN * 1024 * 2);
  bf16*  catp    = act1;                                   // overlay: dead after encoder GEMM
  bf16*  h0      = (bf16*)alloc((size_t)NN * 384 * 2);
  bf16*  h2      = (bf16*)alloc((size_t)NN * 128 * 2);
  bf16*  encWp   = (bf16*)alloc((size_t)416 * 384 * 2);
  bf16*  W1p     = (bf16*)alloc((size_t)384 * 1024 * 2);
  bf16*  W2p     = (bf16*)alloc((size_t)1024 * 128 * 2);
  int*   esrc    = (int*)alloc((size_t)EP * 4);
  int*   edst    = (int*)alloc((size_t)EP * 4);
  int*   csr     = (int*)alloc((size_t)EP * 4);
  // ---- zero-group: one memset covers [eflag .. ad2] ----
  char*  zero_base = ws + off;
  unsigned int* eflag = (unsigned int*)alloc(4);
  unsigned int* fflag = (unsigned int*)alloc(4);
  int*   deg     = (int*)alloc((size_t)NN * 4);
  float* as1     = (float*)alloc((size_t)NN * 4 * 4);
  float* ad1     = (float*)alloc((size_t)NN * 4 * 4);
  float* as2     = (float*)alloc((size_t)NN * 4);
  float* ad2     = (float*)alloc((size_t)NN * 4);
  size_t zero_len = (size_t)((ws + off) - zero_base);
  // ------------------------------------------------------
  int*   row_ptr = (int*)alloc((size_t)(NN + 1) * 4);
  int*   cursor  = (int*)alloc((size_t)NN * 4);
  int*   partial = (int*)alloc((size_t)SCAN_NB * 4);
  (void)ws_size; (void)in_sizes; (void)n_in; (void)out_size;

  (void)hipMemsetAsync(zero_base, 0, zero_len, stream);

  const int EB = (EP + 255) / 256;
  const int MB = (NN + 127) / 128;        // 391 row tiles
  const int XG = (MB + 7) / 8;            // 49 row-tile groups of 8

  // fused dtype detection
  k_detect<<<768, 256, 0, stream>>>((const unsigned int*)ei, (const unsigned int*)x,
                                    eflag, fflag);

  // fused convert(+deg) | pack_cat | pack_w3
  k_fuseA<<<8192, 256, 0, stream>>>(ei, x, na, enc_W, W1, W2,
                                    esrc, edst, deg, catp, encWp, W1p, W2p,
                                    eflag, fflag);

  // CSR build: scan (2 dispatches) + scatter
  k_scan1<<<SCAN_NB, SCAN_B, 0, stream>>>(deg, row_ptr, partial);
  k_scan3b<<<SCAN_NB, SCAN_B, 0, stream>>>(partial, row_ptr, cursor);
  k_scatter<<<EB, 256, 0, stream>>>(esrc, edst, cursor, csr);

  // encoder: [NN x 416] @ [416 x 384] + bias -> h0 (bf16); XCD-swizzled, YB=3
  gemm_mfma<true, false, 1, 3, bf16><<<XG * 3 * 8, 256, 0, stream>>>(
      catp, 416, encWp, enc_b, nullptr, nullptr, nullptr, nullptr,
      h0, NN, 384, 416, fflag);
  // GAT1 transform + fused alpha1: [NN x 384] @ [384 x 1024]; XCD-swizzled, YB=8
  gemm_mfma<false, true, 4, 8, bf16><<<XG * 8 * 8, 256, 0, stream>>>(
      h0, 384, W1p, nullptr, a_src1, a_dst1, as1, ad1,
      h1, NN, 1024, 384, fflag);

  k_agg1<<<NN, 256, 0, stream>>>(csr, row_ptr, as1, ad1, h1, b1, act1, fflag);

  // GAT2 transform + fused alpha2 -> h2 (bf16), as2/ad2 (1 col-tile: no swizzle)
  gemm_mfma<false, true, 1, 0, bf16><<<dim3(MB, 1), 256, 0, stream>>>(
      act1, 1024, W2p, nullptr, a_src2, a_dst2, as2, ad2,
      h2, NN, 128, 1024, fflag);

  k_agg2<<<NN / 4, 256, 0, stream>>>(csr, row_ptr, as2, ad2, h2, b2, out, fflag);
}

// Round 12
// 645.772 us; speedup vs baseline: 1.0112x; 1.0112x over previous
//
#include <hip/hip_runtime.h>
#include <hip/hip_bf16.h>
#include <type_traits>

// ConversationGNN: encoder Linear(386->384) -> GAT(384 -> 4x256 concat) -> ELU
//                  -> GAT(1024 -> 128, 1 head) ; N=50000, E=500000 (+N self loops)
// Round 22: exact revert of round-21's XCD grid swizzle (null-to-negative:
// +6.5us). Back to the round-20 structure — best measured 646.5us:
//   - k_fuseA = convert+pack_cat+pack_w3 (one dispatch, no grid.sync)
//   - k_scan1 + k_scan3b (self-computed chunk prefix) + k_scatter
//   - GEMMs: 128x128 MFMA tiles, global_load_lds width-16 staging, scalar
//     epilogue, fused alpha dot (width-16 shuffle + atomicAdd)
//   - agg kernels in round-12 forms; agg1 pinned at the ~4.05 TB/s
//     random-gather channel ceiling (FETCH 565MB = per-XCD compulsory
//     footprint; three structures bracket it)
// Ledger of closed levers: NT stores (null), batch-8 gather (neg), weight
// composition (neg), coop grid.sync (catastrophic), LDS-staged C-write (neg),
// gload_lds staging (~null), XCD swizzle (null/neg). Dispatch consolidation
// (+38.5us) and non-sync fusion (+7us) were the real wins.

#define NN 50000
#define NE 500000
#define EP (NE + NN)

typedef __hip_bfloat16 bf16;
typedef short short8 __attribute__((ext_vector_type(8)));
typedef __bf16 bf16x8 __attribute__((ext_vector_type(8)));
typedef float f32x4 __attribute__((ext_vector_type(4)));

__device__ __forceinline__ float b2f(bf16 v) { return __bfloat162float(v); }
__device__ __forceinline__ bf16  f2b(float v) { return __float2bfloat16(v); }
__device__ __forceinline__ unsigned short f2bu(float v) {
  bf16 b = __float2bfloat16(v);
  return *reinterpret_cast<unsigned short*>(&b);
}

__device__ __forceinline__ float ldf(const void* p, size_t i, bool f32) {
  return f32 ? ((const float*)p)[i] : b2f(((const bf16*)p)[i]);
}

// unpack two bf16 from one u32 word
__device__ __forceinline__ float bflo(unsigned u) { return __uint_as_float(u << 16); }
__device__ __forceinline__ float bfhi(unsigned u) { return __uint_as_float(u & 0xffff0000u); }

__device__ __forceinline__ float leaky(float v) { return v >= 0.f ? v : 0.2f * v; }

// async 16B global->LDS copy (dest = wave-uniform base + lane*16)
__device__ __forceinline__ void gload_lds16(const void* g, void* l) {
  __builtin_amdgcn_global_load_lds(
      (const __attribute__((address_space(1))) void*)g,
      (__attribute__((address_space(3))) void*)l, 16, 0, 0);
}

// ---------------- fused dtype detection ----------------------------------
__global__ void k_detect(const unsigned int* __restrict__ ei,
                         const unsigned int* __restrict__ xw,
                         unsigned int* __restrict__ eflag,
                         unsigned int* __restrict__ fflag) {
  const int b = blockIdx.x;
  if (b < 512) {
    unsigned int acc = 0;
    for (int i = b * 256 + threadIdx.x; i < NE; i += 512 * 256)
      acc |= ei[2 * i + 1];
    if (acc) atomicOr(eflag, 1u);
  } else {
    unsigned int acc = 0;
    for (int i = (b - 512) * 256 + threadIdx.x; i < (1 << 20); i += 256 * 256) {
      unsigned int e = (xw[i] >> 7) & 0xFF;
      if (e > 0xA0) acc = 1;
    }
    if (acc) atomicOr(fflag, 1u);
  }
}

// ---------------- fused convert + pack (one dispatch) ---------------------
#define PW_S0 (416 * 384)
#define PW_S1 (384 * 1024)
#define PW_S2 (1024 * 128)
#define FUSE_T1 EP
#define FUSE_T2 (FUSE_T1 + NN * 104)
#define FUSE_T3 (FUSE_T2 + PW_S0 + PW_S1 + PW_S2)

__global__ void k_fuseA(const int* __restrict__ ei,
                        const void* __restrict__ x, const void* __restrict__ na,
                        const void* __restrict__ Wenc, const void* __restrict__ W1,
                        const void* __restrict__ W2,
                        int* __restrict__ esrc, int* __restrict__ edst,
                        int* __restrict__ deg,
                        bf16* __restrict__ catp, bf16* __restrict__ encWp,
                        bf16* __restrict__ W1p, bf16* __restrict__ W2p,
                        const unsigned int* __restrict__ eflag,
                        const unsigned int* __restrict__ fflag) {
  const bool ef  = (*eflag != 0);
  const bool f32 = (*fflag != 0);
  for (int g = blockIdx.x * 256 + threadIdx.x; g < FUSE_T3; g += gridDim.x * 256) {
    if (g < FUSE_T1) {
      // convert + degree histogram
      const int e = g;
      int s, d;
      if (e < NE) {
        if (ef) { s = ei[e]; d = ei[NE + e]; }
        else { const long long* e64 = (const long long*)ei; s = (int)e64[e]; d = (int)e64[NE + e]; }
        s = min(max(s, 0), NN - 1);
        d = min(max(d, 0), NN - 1);
      } else {
        s = d = e - NE;
      }
      esrc[e] = s;
      edst[e] = d;
      atomicAdd(&deg[d], 1);
    } else if (g < FUSE_T2) {
      // pack_cat: catp [NN][416] = [x(384); na(2); pad(30)]
      const int gg = g - FUSE_T1;
      int n = gg / 104, r = gg - n * 104;
      int c = r * 4;
      float v0 = 0.f, v1 = 0.f, v2 = 0.f, v3 = 0.f;
      if (c < 384) {
        if (f32) {
          const float4 f = *(const float4*)((const float*)x + (size_t)n * 384 + c);
          v0 = f.x; v1 = f.y; v2 = f.z; v3 = f.w;
        } else {
          const bf16* xb = (const bf16*)x + (size_t)n * 384 + c;
          v0 = b2f(xb[0]); v1 = b2f(xb[1]); v2 = b2f(xb[2]); v3 = b2f(xb[3]);
        }
      } else if (c == 384) {
        v0 = ldf(na, (size_t)n * 2 + 0, f32);
        v1 = ldf(na, (size_t)n * 2 + 1, f32);
      }
      ushort2 o0, o1;
      o0.x = f2bu(v0); o0.y = f2bu(v1);
      o1.x = f2bu(v2); o1.y = f2bu(v3);
      ushort2* dst = (ushort2*)((unsigned short*)catp + (size_t)n * 416 + c);
      dst[0] = o0; dst[1] = o1;
    } else {
      // pack_w3
      int i = g - FUSE_T2;
      const void* W; bf16* Wp; int K, N;
      if (i < PW_S0)               { W = Wenc; Wp = encWp; K = 386;  N = 384;  }
      else if (i < PW_S0 + PW_S1)  { W = W1;   Wp = W1p;   K = 384;  N = 1024; i -= PW_S0; }
      else                         { W = W2;   Wp = W2p;   K = 1024; N = 128;  i -= PW_S0 + PW_S1; }
      int kb = i / (N * 32);
      int rem = i - kb * N * 32;
      int n = rem >> 5, kk = rem & 31;
      int k = kb * 32 + kk;
      float v = (k < K) ? ldf(W, (size_t)k * N + n, f32) : 0.f;
      Wp[i] = f2b(v);
    }
  }
}

// ---------------- CSR scan (2 dispatches) ---------------------------------
#define SCAN_B 512
#define SCAN_NB ((NN + SCAN_B - 1) / SCAN_B)   // 98

__global__ __launch_bounds__(SCAN_B) void k_scan1(const int* __restrict__ deg,
                                                  int* __restrict__ row_ptr,
                                                  int* __restrict__ partial) {
  int b = blockIdx.x, t = threadIdx.x;
  int i = b * SCAN_B + t;
  int v = (i < NN) ? deg[i] : 0;
  int lane = t & 63, w = t >> 6;
  int x = v;
#pragma unroll
  for (int off = 1; off < 64; off <<= 1) {
    int y = __shfl_up(x, off, 64);
    if (lane >= off) x += y;
  }
  __shared__ int ws[8];
  if (lane == 63) ws[w] = x;
  __syncthreads();
  if (t == 0) {
    int run = 0;
#pragma unroll
    for (int j = 0; j < 8; ++j) { int tmp = ws[j]; ws[j] = run; run += tmp; }
    partial[b] = run;
  }
  __syncthreads();
  int excl = x - v + ws[w];
  if (i < NN) row_ptr[i] = excl;
}

// scan3b: each block computes its own chunk-prefix from the 98 partials
// (LDS-cached, uniform loop) — eliminates the separate k_scan2 dispatch.
__global__ __launch_bounds__(SCAN_B) void k_scan3b(const int* __restrict__ partial,
                                                   int* __restrict__ row_ptr,
                                                   int* __restrict__ cursor) {
  const int b = blockIdx.x, t = threadIdx.x;
  __shared__ int sp[SCAN_NB];
  for (int j = t; j < SCAN_NB; j += SCAN_B) sp[j] = partial[j];
  __syncthreads();
  int prefix = 0;
  for (int j = 0; j < b; ++j) prefix += sp[j];   // uniform per block
  const int i = b * SCAN_B + t;
  if (i < NN) {
    int v = row_ptr[i] + prefix;
    row_ptr[i] = v;
    cursor[i] = v;
  }
  if (b == SCAN_NB - 1 && t == 0)
    row_ptr[NN] = prefix + sp[SCAN_NB - 1];       // == EP
}

__global__ void k_scatter(const int* __restrict__ esrc, const int* __restrict__ edst,
                          int* __restrict__ cursor, int* __restrict__ csr) {
  int e = blockIdx.x * 256 + threadIdx.x;
  if (e >= EP) return;
  int pos = atomicAdd(&cursor[edst[e]], 1);
  pos = min(max(pos, 0), EP - 1);
  csr[pos] = esrc[e];
}

// ---------------- MFMA GEMM with fused alpha epilogue --------------------
// Bp packed [K/32][N][32] bf16. N multiple of 128, K multiple of 32.
// 128x128 tile, 4 waves 2x2, each wave 4x4 of 16x16x32 MFMAs.
// Staging: global_load_lds width-16 into LINEAR LDS tiles [128][32].
// C-write: scalar epilogue. ALPHA: width-16 shuffle reduce + atomicAdd.
template<bool ADD_BIAS, bool ALPHA, int NH, typename CT>
__global__ __launch_bounds__(256) void gemm_mfma(
    const bf16* __restrict__ A, int lda,
    const bf16* __restrict__ Bp,
    const void* __restrict__ bias,
    const void* __restrict__ a_srcp, const void* __restrict__ a_dstp,
    float* __restrict__ as_out, float* __restrict__ ad_out,
    CT* __restrict__ C,
    int M, int N, int K,
    const unsigned int* __restrict__ fflag) {
  const bool xf32 = (ADD_BIAS || ALPHA) ? (*fflag != 0) : false;
  __shared__ short As[128 * 32];
  __shared__ short Bs[128 * 32];
  const int t = threadIdx.x;
  const int lane = t & 63, wave = t >> 6;
  const int wm = wave & 1, wn = wave >> 1;
  const int quad = lane >> 4, l15 = lane & 15;
  const int m0 = blockIdx.x * 128, n0 = blockIdx.y * 128;

  f32x4 acc[4][4];
#pragma unroll
  for (int i = 0; i < 4; ++i)
#pragma unroll
    for (int j = 0; j < 4; ++j) acc[i][j] = (f32x4){0.f, 0.f, 0.f, 0.f};

  // per-thread staging geometry (k-invariant)
  const int c0 = t, c1 = t + 256;
  const int arow0 = min(m0 + (c0 >> 2), M - 1), akoff0 = (c0 & 3) * 8;
  const int arow1 = min(m0 + (c1 >> 2), M - 1), akoff1 = (c1 & 3) * 8;

  for (int k0 = 0; k0 < K; k0 += 32) {
    gload_lds16((const short*)A + (size_t)arow0 * lda + k0 + akoff0, &As[c0 * 8]);
    gload_lds16((const short*)A + (size_t)arow1 * lda + k0 + akoff1, &As[c1 * 8]);
    {
      const short* base = (const short*)Bp + ((size_t)(k0 >> 5) * N + n0) * 32;
      gload_lds16(base + c0 * 8, &Bs[c0 * 8]);
      gload_lds16(base + c1 * 8, &Bs[c1 * 8]);
    }
    __syncthreads();
    bf16x8 af[4], bfr[4];
#pragma unroll
    for (int mi = 0; mi < 4; ++mi)
      af[mi] = *reinterpret_cast<const bf16x8*>(&As[(wm * 64 + mi * 16 + l15) * 32 + quad * 8]);
#pragma unroll
    for (int ni = 0; ni < 4; ++ni)
      bfr[ni] = *reinterpret_cast<const bf16x8*>(&Bs[(wn * 64 + ni * 16 + l15) * 32 + quad * 8]);
#pragma unroll
    for (int mi = 0; mi < 4; ++mi)
#pragma unroll
      for (int ni = 0; ni < 4; ++ni)
        acc[mi][ni] = __builtin_amdgcn_mfma_f32_16x16x32_bf16(af[mi], bfr[ni], acc[mi][ni], 0, 0, 0);
    __syncthreads();
  }

  // C write (C/D layout: col=lane&15, row=quad*4+reg)
#pragma unroll
  for (int mi = 0; mi < 4; ++mi) {
#pragma unroll
    for (int ni = 0; ni < 4; ++ni) {
      const int gn = n0 + wn * 64 + ni * 16 + l15;
      float bv = ADD_BIAS ? ldf(bias, gn, xf32) : 0.f;
#pragma unroll
      for (int r = 0; r < 4; ++r) {
        const int gm = m0 + wm * 64 + mi * 16 + quad * 4 + r;
        if (gm < M) {
          float v = acc[mi][ni][r] + bv;
          if constexpr (std::is_same<CT, float>::value)
            C[(size_t)gm * N + gn] = v;
          else
            C[(size_t)gm * N + gn] = f2b(v);
        }
      }
    }
  }

  if (ALPHA) {
    // a_src/a_dst flat [N]: flat index == gn for both layer shapes.
    float avs[4], avd[4];
#pragma unroll
    for (int ni = 0; ni < 4; ++ni) {
      const int gn = n0 + wn * 64 + ni * 16 + l15;
      avs[ni] = ldf(a_srcp, gn, xf32);
      avd[ni] = ldf(a_dstp, gn, xf32);
    }
    const int head = (n0 + wn * 64) >> 8;
#pragma unroll
    for (int mi = 0; mi < 4; ++mi) {
#pragma unroll
      for (int r = 0; r < 4; ++r) {
        float ps = 0.f, pd = 0.f;
#pragma unroll
        for (int ni = 0; ni < 4; ++ni) {
          const float v = acc[mi][ni][r];
          ps = fmaf(v, avs[ni], ps);
          pd = fmaf(v, avd[ni], pd);
        }
#pragma unroll
        for (int off = 8; off > 0; off >>= 1) {
          ps += __shfl_down(ps, off, 16);
          pd += __shfl_down(pd, off, 16);
        }
        if (l15 == 0) {
          const int gm = m0 + wm * 64 + mi * 16 + quad * 4 + r;
          if (gm < M) {
            atomicAdd(&as_out[gm * NH + head], ps);
            atomicAdd(&ad_out[gm * NH + head], pd);
          }
        }
      }
    }
  }
}

// ---------------- fused softmax + aggregation ----------------------------
// k_agg1: block = dst node n; wave w = head w; lane l covers cols
// w*128+l*2 (two dwords = 4 bf16). Batch-4 + serial tail (round-12 form —
// measured best; agg1 is at the ~4.05 TB/s random-gather channel ceiling).
__global__ __launch_bounds__(256) void k_agg1(
    const int* __restrict__ csr, const int* __restrict__ row_ptr,
    const float* __restrict__ as1, const float* __restrict__ ad1,
    const bf16* __restrict__ h1, const void* __restrict__ b1,
    bf16* __restrict__ act1, const unsigned int* __restrict__ fflag) {
  const bool f32 = (*fflag != 0);
  const int n = blockIdx.x, t = threadIdx.x;
  const int w = t >> 6, l = t & 63;
  const int start = row_ptr[n], end = row_ptr[n + 1];
  const float adn = ad1[n * 4 + w];
  const unsigned* hb = (const unsigned*)h1;
  const int coff = w * 128 + l * 2;

  float a0 = 0.f, a1 = 0.f, a2 = 0.f, a3 = 0.f, densum = 0.f;

  int idx = start;
  for (; idx + 4 <= end; idx += 4) {
    int s0 = csr[idx], s1 = csr[idx + 1], s2 = csr[idx + 2], s3 = csr[idx + 3];
    uint2 w0 = *(const uint2*)(hb + (size_t)s0 * 512 + coff);
    uint2 w1 = *(const uint2*)(hb + (size_t)s1 * 512 + coff);
    uint2 w2 = *(const uint2*)(hb + (size_t)s2 * 512 + coff);
    uint2 w3 = *(const uint2*)(hb + (size_t)s3 * 512 + coff);
    float p0 = __expf(leaky(as1[s0 * 4 + w] + adn));
    float p1 = __expf(leaky(as1[s1 * 4 + w] + adn));
    float p2 = __expf(leaky(as1[s2 * 4 + w] + adn));
    float p3 = __expf(leaky(as1[s3 * 4 + w] + adn));
    densum += (p0 + p1) + (p2 + p3);
    a0 = fmaf(bflo(w0.x), p0, a0); a1 = fmaf(bfhi(w0.x), p0, a1);
    a2 = fmaf(bflo(w0.y), p0, a2); a3 = fmaf(bfhi(w0.y), p0, a3);
    a0 = fmaf(bflo(w1.x), p1, a0); a1 = fmaf(bfhi(w1.x), p1, a1);
    a2 = fmaf(bflo(w1.y), p1, a2); a3 = fmaf(bfhi(w1.y), p1, a3);
    a0 = fmaf(bflo(w2.x), p2, a0); a1 = fmaf(bfhi(w2.x), p2, a1);
    a2 = fmaf(bflo(w2.y), p2, a2); a3 = fmaf(bfhi(w2.y), p2, a3);
    a0 = fmaf(bflo(w3.x), p3, a0); a1 = fmaf(bfhi(w3.x), p3, a1);
    a2 = fmaf(bflo(w3.y), p3, a2); a3 = fmaf(bfhi(w3.y), p3, a3);
  }
  for (; idx < end; ++idx) {
    int s0 = csr[idx];
    uint2 w0 = *(const uint2*)(hb + (size_t)s0 * 512 + coff);
    float p0 = __expf(leaky(as1[s0 * 4 + w] + adn));
    densum += p0;
    a0 = fmaf(bflo(w0.x), p0, a0); a1 = fmaf(bfhi(w0.x), p0, a1);
    a2 = fmaf(bflo(w0.y), p0, a2); a3 = fmaf(bfhi(w0.y), p0, a3);
  }

  const float inv = 1.f / (densum + 1e-16f);
  const int col = w * 256 + l * 4;
  float v0 = a0 * inv + ldf(b1, col + 0, f32);
  float v1 = a1 * inv + ldf(b1, col + 1, f32);
  float v2 = a2 * inv + ldf(b1, col + 2, f32);
  float v3 = a3 * inv + ldf(b1, col + 3, f32);
  v0 = v0 > 0.f ? v0 : expm1f(v0);
  v1 = v1 > 0.f ? v1 : expm1f(v1);
  v2 = v2 > 0.f ? v2 : expm1f(v2);
  v3 = v3 > 0.f ? v3 : expm1f(v3);
  unsigned lo = (unsigned)f2bu(v0) | ((unsigned)f2bu(v1) << 16);
  unsigned hi = (unsigned)f2bu(v2) | ((unsigned)f2bu(v3) << 16);
  unsigned long long ow = (unsigned long long)lo | ((unsigned long long)hi << 32);
  __builtin_nontemporal_store(
      ow, (unsigned long long*)((unsigned short*)act1 + (size_t)n * 1024 + col));
}

// k_agg2: ONE WAVE PER NODE (4 nodes / block). Lane l covers channels
// 2l, 2l+1 of the 128-wide h2 row (one dword load per edge). Single head.
// readfirstlane batch-2 (round-12 form). NT store out.
__global__ __launch_bounds__(256) void k_agg2(
    const int* __restrict__ csr, const int* __restrict__ row_ptr,
    const float* __restrict__ as2, const float* __restrict__ ad2,
    const bf16* __restrict__ h2, const void* __restrict__ b2v,
    float* __restrict__ out, const unsigned int* __restrict__ fflag) {
  const bool f32 = (*fflag != 0);
  const int t = threadIdx.x;
  const int wv = t >> 6, l = t & 63;
  const int n = blockIdx.x * 4 + wv;
  const int start = row_ptr[n], end = row_ptr[n + 1];
  const float adn = ad2[n];
  const unsigned* hb = (const unsigned*)h2;   // 64 words per row
  float a0 = 0.f, a1 = 0.f, densum = 0.f;

  int idx = start;
  for (; idx + 2 <= end; idx += 2) {
    const int s0 = __builtin_amdgcn_readfirstlane(csr[idx]);
    const int s1 = __builtin_amdgcn_readfirstlane(csr[idx + 1]);
    const unsigned w0 = hb[(size_t)s0 * 64 + l];
    const unsigned w1 = hb[(size_t)s1 * 64 + l];
    const float p0 = __expf(leaky(as2[s0] + adn));
    const float p1 = __expf(leaky(as2[s1] + adn));
    densum += p0 + p1;
    a0 = fmaf(bflo(w0), p0, a0); a1 = fmaf(bfhi(w0), p0, a1);
    a0 = fmaf(bflo(w1), p1, a0); a1 = fmaf(bfhi(w1), p1, a1);
  }
  if (idx < end) {
    const int s0 = __builtin_amdgcn_readfirstlane(csr[idx]);
    const unsigned w0 = hb[(size_t)s0 * 64 + l];
    const float p0 = __expf(leaky(as2[s0] + adn));
    densum += p0;
    a0 = fmaf(bflo(w0), p0, a0); a1 = fmaf(bfhi(w0), p0, a1);
  }

  const float inv = 1.f / (densum + 1e-16f);
  float2 o;
  o.x = a0 * inv + ldf(b2v, l * 2 + 0, f32);
  o.y = a1 * inv + ldf(b2v, l * 2 + 1, f32);
  unsigned long long u;
  __builtin_memcpy(&u, &o, 8);
  __builtin_nontemporal_store(u, (unsigned long long*)(out + (size_t)n * 128 + l * 2));
}

// ---------------- launch --------------------------------------------------
extern "C" void kernel_launch(void* const* d_in, const int* in_sizes, int n_in,
                              void* d_out, int out_size, void* d_ws, size_t ws_size,
                              hipStream_t stream) {
  const void* x       = d_in[0];
  const void* na      = d_in[1];
  const int*  ei      = (const int*)d_in[2];
  const void* enc_W   = d_in[3];
  const void* enc_b   = d_in[4];
  const void* W1      = d_in[5];
  const void* a_src1  = d_in[6];
  const void* a_dst1  = d_in[7];
  const void* b1      = d_in[8];
  const void* W2      = d_in[9];
  const void* a_src2  = d_in[10];
  const void* a_dst2  = d_in[11];
  const void* b2      = d_in[12];
  float* out = (float*)d_out;

  size_t off = 0;
  char* ws = (char*)d_ws;
  auto alloc = [&](size_t bytes) -> void* {
    void* p = ws + off;
    off += (bytes + 255) & ~(size_t)255;
    return p;
  };
  bf16*  h1      = (bf16*)alloc((size_t)NN * 1024 * 2);
  bf16*  act1    = (bf16*)alloc((size_t)NN * 1024 * 2);
  bf16*  catp    = act1;                                   // overlay: dead after encoder GEMM
  bf16*  h0      = (bf16*)alloc((size_t)NN * 384 * 2);
  bf16*  h2      = (bf16*)alloc((size_t)NN * 128 * 2);
  bf16*  encWp   = (bf16*)alloc((size_t)416 * 384 * 2);
  bf16*  W1p     = (bf16*)alloc((size_t)384 * 1024 * 2);
  bf16*  W2p     = (bf16*)alloc((size_t)1024 * 128 * 2);
  int*   esrc    = (int*)alloc((size_t)EP * 4);
  int*   edst    = (int*)alloc((size_t)EP * 4);
  int*   csr     = (int*)alloc((size_t)EP * 4);
  // ---- zero-group: one memset covers [eflag .. ad2] ----
  char*  zero_base = ws + off;
  unsigned int* eflag = (unsigned int*)alloc(4);
  unsigned int* fflag = (unsigned int*)alloc(4);
  int*   deg     = (int*)alloc((size_t)NN * 4);
  float* as1     = (float*)alloc((size_t)NN * 4 * 4);
  float* ad1     = (float*)alloc((size_t)NN * 4 * 4);
  float* as2     = (float*)alloc((size_t)NN * 4);
  float* ad2     = (float*)alloc((size_t)NN * 4);
  size_t zero_len = (size_t)((ws + off) - zero_base);
  // ------------------------------------------------------
  int*   row_ptr = (int*)alloc((size_t)(NN + 1) * 4);
  int*   cursor  = (int*)alloc((size_t)NN * 4);
  int*   partial = (int*)alloc((size_t)SCAN_NB * 4);
  (void)ws_size; (void)in_sizes; (void)n_in; (void)out_size;

  (void)hipMemsetAsync(zero_base, 0, zero_len, stream);

  const int EB = (EP + 255) / 256;
  const int MB = (NN + 127) / 128;

  // fused dtype detection
  k_detect<<<768, 256, 0, stream>>>((const unsigned int*)ei, (const unsigned int*)x,
                                    eflag, fflag);

  // fused convert(+deg) | pack_cat | pack_w3
  k_fuseA<<<8192, 256, 0, stream>>>(ei, x, na, enc_W, W1, W2,
                                    esrc, edst, deg, catp, encWp, W1p, W2p,
                                    eflag, fflag);

  // CSR build: scan (2 dispatches) + scatter
  k_scan1<<<SCAN_NB, SCAN_B, 0, stream>>>(deg, row_ptr, partial);
  k_scan3b<<<SCAN_NB, SCAN_B, 0, stream>>>(partial, row_ptr, cursor);
  k_scatter<<<EB, 256, 0, stream>>>(esrc, edst, cursor, csr);

  // encoder: [NN x 416] @ [416 x 384] + bias -> h0 (bf16)
  gemm_mfma<true, false, 1, bf16><<<dim3(MB, 3), 256, 0, stream>>>(
      catp, 416, encWp, enc_b, nullptr, nullptr, nullptr, nullptr,
      h0, NN, 384, 416, fflag);
  // GAT1 transform + fused alpha1: [NN x 384] @ [384 x 1024] -> h1, as1/ad1
  gemm_mfma<false, true, 4, bf16><<<dim3(MB, 8), 256, 0, stream>>>(
      h0, 384, W1p, nullptr, a_src1, a_dst1, as1, ad1,
      h1, NN, 1024, 384, fflag);

  k_agg1<<<NN, 256, 0, stream>>>(csr, row_ptr, as1, ad1, h1, b1, act1, fflag);

  // GAT2 transform + fused alpha2 -> h2 (bf16), as2/ad2
  gemm_mfma<false, true, 1, bf16><<<dim3(MB, 1), 256, 0, stream>>>(
      act1, 1024, W2p, nullptr, a_src2, a_dst2, as2, ad2,
      h2, NN, 128, 1024, fflag);

  k_agg2<<<NN / 4, 256, 0, stream>>>(csr, row_ptr, as2, ad2, h2, b2, out, fflag);
}